// Round 7
// baseline (514.948 us; speedup 1.0000x reference)
//
#include <hip/hip_runtime.h>
#include <hip/hip_bf16.h>
#include <math.h>

typedef __bf16 bf16_t;
typedef bf16_t bf16x8 __attribute__((ext_vector_type(8)));
typedef float  f32x4  __attribute__((ext_vector_type(4)));

static constexpr int Bn = 16384;
static constexpr int Hn = 512;

__device__ __forceinline__ float sigm(float x) { return 1.0f / (1.0f + __expf(-x)); }

typedef __attribute__((address_space(3))) void lds_void;
typedef const __attribute__((address_space(1))) void gl_void;

__device__ __forceinline__ void glds16(const void* g, void* l) {
    __builtin_amdgcn_global_load_lds((gl_void*)g, (lds_void*)l, 16, 0, 0);
}

// comb[B][1024] bf16 = [input | hidden]
__global__ void convert_comb(const float* __restrict__ inp, const float* __restrict__ hid,
                             bf16_t* __restrict__ comb)
{
    size_t t = (size_t)blockIdx.x * blockDim.x + threadIdx.x;
    size_t r = t >> 7;
    int c8 = (int)(t & 127);
    const float* src = (c8 < 64) ? (inp + r * 512 + c8 * 8) : (hid + r * 512 + (c8 - 64) * 8);
    float4 a = ((const float4*)src)[0];
    float4 b = ((const float4*)src)[1];
    bf16x8 o;
    o[0] = (bf16_t)a.x; o[1] = (bf16_t)a.y; o[2] = (bf16_t)a.z; o[3] = (bf16_t)a.w;
    o[4] = (bf16_t)b.x; o[5] = (bf16_t)b.y; o[6] = (bf16_t)b.z; o[7] = (bf16_t)b.w;
    *(bf16x8*)(comb + t * 8) = o;
}

// All three weight transposes in one launch.
__global__ void transpose_all(const float* __restrict__ Wg, bf16_t* __restrict__ WgT,
                              const float* __restrict__ Wa, bf16_t* __restrict__ WaT,
                              const float* __restrict__ Mem, bf16_t* __restrict__ MemT)
{
    __shared__ float tile[32][33];
    int b = blockIdx.x;
    const float* src; bf16_t* dst; int R, C, gx;
    if (b < 2048)      { src = Wg;  dst = WgT;  R = 1024; C = 2048; gx = 64; }
    else if (b < 4096) { b -= 2048; src = Wa;  dst = WaT;  R = 512;  C = 4096; gx = 128; }
    else               { b -= 4096; src = Mem; dst = MemT; R = 4096; C = 512;  gx = 16; }
    const int x0 = (b % gx) * 32, y0 = (b / gx) * 32;
    const int tx = threadIdx.x & 31, ty = threadIdx.x >> 5;
#pragma unroll
    for (int i = 0; i < 32; i += 8)
        tile[ty + i][tx] = src[(size_t)(y0 + ty + i) * C + x0 + tx];
    __syncthreads();
#pragma unroll
    for (int i = 0; i < 32; i += 8)
        dst[(size_t)(x0 + ty + i) * R + y0 + tx] = (bf16_t)tile[tx][ty + i];
}

// C[M,N] = epi(A @ Bt^T + bias). 128x256 tile, BK=64, 8 waves (2x4), 512 threads.
// DOUBLE-BUFFERED LDS + counted vmcnt (never 0 in-loop) + raw s_barrier (no drain).
// LDS rows 128B = 8 x 16B slots, swizzle slot ^= (row&7); linear glds dest +
// inverse-swizzled source + swizzled ds_read (involution).
template<int EPI>
__global__ __launch_bounds__(512)
void gemm_w8(const bf16_t* __restrict__ A, int lda,
             const bf16_t* __restrict__ Bt, int ldb,
             const float* __restrict__ bias, int K, int N,
             bf16_t* __restrict__ bout, int ost)
{
    __shared__ __align__(16) bf16_t sA[2][128 * 64];   // 2 x 16 KB
    __shared__ __align__(16) bf16_t sB[2][256 * 64];   // 2 x 32 KB

    const int tid = threadIdx.x, lane = tid & 63, wid = tid >> 6;
    const int wr = wid >> 2, wc = wid & 3;              // 2x4 waves

    const int nwg = gridDim.x;
    int bid = (blockIdx.x & 7) * (nwg >> 3) + (blockIdx.x >> 3);  // XCD swizzle
    const int cbn = N >> 8;
    const int row0 = (bid / cbn) * 128, col0 = (bid % cbn) * 256;

    f32x4 acc[4][4] = {};
    const int nk = K >> 6;
    const int l15 = lane & 15, kq = lane >> 4;
    const int sslot = (lane & 7) ^ (lane >> 3);         // staging source swizzle

    auto stage = [&](int b, int kt) {
        const int k0 = kt << 6;
#pragma unroll
        for (int t = 0; t < 2; ++t) {                   // A: 16 chunks, 2/wave
            const int c8 = wid * 2 + t;
            const int r = c8 * 8 + (lane >> 3);
            glds16(A + (size_t)(row0 + r) * lda + k0 + sslot * 8, &sA[b][c8 * 512]);
        }
#pragma unroll
        for (int t = 0; t < 4; ++t) {                   // B: 32 chunks, 4/wave
            const int c8 = wid * 4 + t;
            const int r = c8 * 8 + (lane >> 3);
            glds16(Bt + (size_t)(col0 + r) * ldb + k0 + sslot * 8, &sB[b][c8 * 512]);
        }
    };

    auto compute = [&](int b) {
#pragma unroll
        for (int ks = 0; ks < 2; ++ks) {
            bf16x8 af[4], bfr[4];
            const int slot = (ks * 4 + kq) ^ (l15 & 7);
#pragma unroll
            for (int j = 0; j < 4; ++j) {
                const int rb = wc * 64 + j * 16 + l15;
                bfr[j] = *(const bf16x8*)&sB[b][rb * 64 + slot * 8];
                const int ra = wr * 64 + j * 16 + l15;
                af[j] = *(const bf16x8*)&sA[b][ra * 64 + slot * 8];
            }
#pragma unroll
            for (int i = 0; i < 4; ++i)
#pragma unroll
                for (int j = 0; j < 4; ++j)
                    acc[i][j] = __builtin_amdgcn_mfma_f32_16x16x32_bf16(af[i], bfr[j], acc[i][j], 0, 0, 0);
        }
    };

    stage(0, 0);
    for (int kt = 0; kt < nk - 1; ++kt) {
        stage((kt + 1) & 1, kt + 1);                    // prefetch next tile
        asm volatile("s_waitcnt vmcnt(6)" ::: "memory"); // wait only cur tile's 6 loads
        __builtin_amdgcn_sched_barrier(0);
        __builtin_amdgcn_s_barrier();
        compute(kt & 1);
        __builtin_amdgcn_sched_barrier(0);              // pin reads above barrier
        __builtin_amdgcn_s_barrier();
    }
    asm volatile("s_waitcnt vmcnt(0)" ::: "memory");
    __builtin_amdgcn_sched_barrier(0);
    __builtin_amdgcn_s_barrier();
    compute((nk - 1) & 1);

    const int lr = (lane >> 4) * 4, lc = lane & 15;
#pragma unroll
    for (int i = 0; i < 4; ++i) {
#pragma unroll
        for (int j = 0; j < 4; ++j) {
#pragma unroll
            for (int r = 0; r < 4; ++r) {
                const int grow = row0 + wr * 64 + i * 16 + lr + r;
                const int gcol = col0 + wc * 64 + j * 16 + lc;
                float v = acc[i][j][r] + bias[gcol];
                if constexpr (EPI == 0) {
                    const float a = ((gcol >> 9) == 2) ? tanhf(v) : sigm(v);
                    bout[(size_t)grow * 2048 + gcol] = (bf16_t)a;
                } else {
                    bout[(size_t)grow * ost + gcol] = (bf16_t)v;
                }
            }
        }
    }
}

// mr = attn_bf16 @ MemT^T fused with LSTM update. 64x256 tile, BK=64, 8 waves (2x4).
// Same double-buffered counted-vmcnt pipeline.
__global__ __launch_bounds__(512)
void gemm3k(const bf16_t* __restrict__ Ap, int astride,
            const bf16_t* __restrict__ MemT,
            const bf16_t* __restrict__ gates, const float* __restrict__ cell,
            float* __restrict__ fout)
{
    __shared__ __align__(16) bf16_t sA[2][64 * 64];     // 2 x 8 KB
    __shared__ __align__(16) bf16_t sB[2][256 * 64];    // 2 x 32 KB

    const int tid = threadIdx.x, lane = tid & 63, wid = tid >> 6;
    const int wr = wid >> 2, wc = wid & 3;

    int bid = (blockIdx.x & 7) * 64 + (blockIdx.x >> 3);   // 512 blocks
    const int row0 = (bid >> 1) * 64, col0 = (bid & 1) * 256;

    f32x4 acc[2][4] = {};
    const int l15 = lane & 15, kq = lane >> 4;
    const int sslot = (lane & 7) ^ (lane >> 3);

    auto stage = [&](int b, int kt) {
        const int k0 = kt << 6;
        {   // A: 8 chunks, 1/wave
            const int c8 = wid;
            const int r = c8 * 8 + (lane >> 3);
            glds16(Ap + (size_t)(row0 + r) * astride + k0 + sslot * 8, &sA[b][c8 * 512]);
        }
#pragma unroll
        for (int t = 0; t < 4; ++t) {                   // B: 32 chunks, 4/wave
            const int c8 = wid * 4 + t;
            const int r = c8 * 8 + (lane >> 3);
            glds16(MemT + (size_t)(col0 + r) * 4096 + k0 + sslot * 8, &sB[b][c8 * 512]);
        }
    };

    auto compute = [&](int b) {
#pragma unroll
        for (int ks = 0; ks < 2; ++ks) {
            bf16x8 af[2], bfr[4];
            const int sl = (ks * 4 + kq) ^ (l15 & 7);
#pragma unroll
            for (int j = 0; j < 4; ++j) {
                const int rb = wc * 64 + j * 16 + l15;
                bfr[j] = *(const bf16x8*)&sB[b][rb * 64 + sl * 8];
            }
#pragma unroll
            for (int i = 0; i < 2; ++i) {
                const int ra = wr * 32 + i * 16 + l15;
                af[i] = *(const bf16x8*)&sA[b][ra * 64 + sl * 8];
            }
#pragma unroll
            for (int i = 0; i < 2; ++i)
#pragma unroll
                for (int j = 0; j < 4; ++j)
                    acc[i][j] = __builtin_amdgcn_mfma_f32_16x16x32_bf16(af[i], bfr[j], acc[i][j], 0, 0, 0);
        }
    };

    stage(0, 0);
    for (int kt = 0; kt < 63; ++kt) {
        stage((kt + 1) & 1, kt + 1);
        asm volatile("s_waitcnt vmcnt(5)" ::: "memory");
        __builtin_amdgcn_sched_barrier(0);
        __builtin_amdgcn_s_barrier();
        compute(kt & 1);
        __builtin_amdgcn_sched_barrier(0);
        __builtin_amdgcn_s_barrier();
    }
    asm volatile("s_waitcnt vmcnt(0)" ::: "memory");
    __builtin_amdgcn_sched_barrier(0);
    __builtin_amdgcn_s_barrier();
    compute(1);                                         // (64-1)&1

    const int lr = (lane >> 4) * 4, lc = lane & 15;
#pragma unroll
    for (int i = 0; i < 2; ++i) {
#pragma unroll
        for (int j = 0; j < 4; ++j) {
#pragma unroll
            for (int r = 0; r < 4; ++r) {
                const int grow = row0 + wr * 32 + i * 16 + lr + r;
                const int gcol = col0 + wc * 64 + j * 16 + lc;
                const float v = acc[i][j][r];
                const float ig = (float)gates[(size_t)grow * 2048 + gcol];
                const float fg = (float)gates[(size_t)grow * 2048 + 512 + gcol];
                const float cg = (float)gates[(size_t)grow * 2048 + 1024 + gcol];
                const float og = (float)gates[(size_t)grow * 2048 + 1536 + gcol];
                const float cv = cell[(size_t)grow * 512 + gcol];
                const float ncv = fg * cv + ig * cg + 0.1f * v;
                fout[(size_t)grow * 512 + gcol] = og * tanhf(ncv);
                fout[(size_t)Bn * Hn + (size_t)grow * 512 + gcol] = ncv;
            }
        }
    }
}

// Row softmax over packed bf16 logits (stride pstride). Writes bf16 attn back in
// place; if F32OUT also writes the full fp32 attn row to attnf32.
template<bool F32OUT>
__global__ void softmax_k(bf16_t* __restrict__ packed, int pstride, float* __restrict__ attnf32)
{
    const int row = blockIdx.x;
    bf16_t* lp = packed + (size_t)row * pstride;
    const int tid = threadIdx.x;

    float v[16];
    {
        bf16x8 h0 = ((const bf16x8*)lp)[tid];
        bf16x8 h1 = ((const bf16x8*)lp)[tid + 256];
#pragma unroll
        for (int k = 0; k < 8; ++k) { v[k] = (float)h0[k]; v[8 + k] = (float)h1[k]; }
    }
    float mx = v[0];
#pragma unroll
    for (int k = 1; k < 16; ++k) mx = fmaxf(mx, v[k]);
#pragma unroll
    for (int off = 32; off > 0; off >>= 1) mx = fmaxf(mx, __shfl_xor(mx, off));
    __shared__ float smx[4], ssm[4];
    if ((tid & 63) == 0) smx[tid >> 6] = mx;
    __syncthreads();
    mx = fmaxf(fmaxf(smx[0], smx[1]), fmaxf(smx[2], smx[3]));

    float sum = 0.0f;
#pragma unroll
    for (int k = 0; k < 16; ++k) { v[k] = __expf(v[k] - mx); sum += v[k]; }
#pragma unroll
    for (int off = 32; off > 0; off >>= 1) sum += __shfl_xor(sum, off);
    if ((tid & 63) == 0) ssm[tid >> 6] = sum;
    __syncthreads();
    sum = ssm[0] + ssm[1] + ssm[2] + ssm[3];

    const float inv = 1.0f / sum;
#pragma unroll
    for (int k = 0; k < 16; ++k) v[k] *= inv;

    bf16x8 o0, o1;
#pragma unroll
    for (int k = 0; k < 8; ++k) { o0[k] = (bf16_t)v[k]; o1[k] = (bf16_t)v[8 + k]; }
    ((bf16x8*)lp)[tid]       = o0;
    ((bf16x8*)lp)[tid + 256] = o1;

    if constexpr (F32OUT) {
        float* rp = attnf32 + (size_t)row * 4096;
        float4 a0 = { v[0], v[1], v[2], v[3] },   a1 = { v[4], v[5], v[6], v[7] };
        float4 a2 = { v[8], v[9], v[10], v[11] }, a3 = { v[12], v[13], v[14], v[15] };
        ((float4*)rp)[2 * tid]             = a0;
        ((float4*)rp)[2 * tid + 1]         = a1;
        ((float4*)rp)[2 * (tid + 256)]     = a2;
        ((float4*)rp)[2 * (tid + 256) + 1] = a3;
    }
}

// Expand packed bf16 attn row (first half) -> full fp32 row, in place (fallback).
__global__ void expand_attn(float* __restrict__ attn)
{
    const int row = blockIdx.x;
    float* rp = attn + (size_t)row * 4096;
    const int t = threadIdx.x;
    bf16x8 h0 = ((const bf16x8*)rp)[2 * t];
    bf16x8 h1 = ((const bf16x8*)rp)[2 * t + 1];
    __syncthreads();
    float4 o0 = { (float)h0[0], (float)h0[1], (float)h0[2], (float)h0[3] };
    float4 o1 = { (float)h0[4], (float)h0[5], (float)h0[6], (float)h0[7] };
    float4 o2 = { (float)h1[0], (float)h1[1], (float)h1[2], (float)h1[3] };
    float4 o3 = { (float)h1[4], (float)h1[5], (float)h1[6], (float)h1[7] };
    ((float4*)rp)[4 * t]     = o0;
    ((float4*)rp)[4 * t + 1] = o1;
    ((float4*)rp)[4 * t + 2] = o2;
    ((float4*)rp)[4 * t + 3] = o3;
}

extern "C" void kernel_launch(void* const* d_in, const int* in_sizes, int n_in,
                              void* d_out, int out_size, void* d_ws, size_t ws_size,
                              hipStream_t stream)
{
    const float* input  = (const float*)d_in[0];
    const float* hidden = (const float*)d_in[1];
    const float* cell   = (const float*)d_in[2];
    const float* Wg     = (const float*)d_in[3];
    const float* bg     = (const float*)d_in[4];
    const float* Wa     = (const float*)d_in[5];
    const float* ba     = (const float*)d_in[6];
    const float* Mem    = (const float*)d_in[7];

    float* out  = (float*)d_out;
    float* attn = out + 2ull * Bn * Hn;

    bf16_t* comb  = (bf16_t*)d_ws;                 // [B][1024]      33.5 MB
    bf16_t* WgT   = comb + (size_t)Bn * 1024;      // [2048][1024]    4.2
    bf16_t* WaT   = WgT + (size_t)2048 * 1024;     // [4096][512]     4.2
    bf16_t* MemT  = WaT + (size_t)4096 * 512;      // [512][4096]     4.2
    bf16_t* gates = MemT + (size_t)512 * 4096;     // [B][2048]      67.1
    bf16_t* pws   = gates + (size_t)Bn * 2048;     // [B][4096]     134.2 (big path)

    const size_t need_big = ((size_t)Bn * 1024 + 2048 * 1024 + 4096 * 512 + 512 * 4096
                             + (size_t)Bn * 2048 + (size_t)Bn * 4096) * sizeof(bf16_t);
    const bool big = ws_size >= need_big;
    bf16_t* packed = big ? pws : (bf16_t*)attn;
    const int pstride = big ? 4096 : 8192;

    convert_comb<<<8192, 256, 0, stream>>>(input, hidden, comb);
    transpose_all<<<6144, 256, 0, stream>>>(Wg, WgT, Wa, WaT, Mem, MemT);

    // gates = act([x|h] @ Wg + bg): 128x256 tiles, grid 128x8
    gemm_w8<0><<<1024, 512, 0, stream>>>(comb, 1024, WgT, 1024, bg, 1024, 2048, gates, 2048);
    // logits = h @ Wa + ba (packed bf16): grid 128x16
    gemm_w8<1><<<2048, 512, 0, stream>>>(comb + 512, 1024, WaT, 512, ba, 512, 4096,
                                         packed, pstride);

    if (big) softmax_k<true><<<Bn, 256, 0, stream>>>(packed, pstride, attn);
    else     softmax_k<false><<<Bn, 256, 0, stream>>>(packed, pstride, nullptr);

    // mr = attn @ Mem fused with LSTM update: 64x256 tiles, grid 256x2
    gemm3k<<<512, 512, 0, stream>>>(packed, pstride, MemT, gates, cell, out);

    if (!big) expand_attn<<<Bn, 256, 0, stream>>>(attn);
}

// Round 8
// 492.590 us; speedup vs baseline: 1.0454x; 1.0454x over previous
//
#include <hip/hip_runtime.h>
#include <hip/hip_bf16.h>
#include <math.h>

typedef __bf16 bf16_t;
typedef bf16_t bf16x8 __attribute__((ext_vector_type(8)));
typedef float  f32x4  __attribute__((ext_vector_type(4)));

static constexpr int Bn = 16384;
static constexpr int Hn = 512;

__device__ __forceinline__ float sigm(float x) { return 1.0f / (1.0f + __expf(-x)); }

typedef __attribute__((address_space(3))) void lds_void;
typedef const __attribute__((address_space(1))) void gl_void;

__device__ __forceinline__ void glds16(const void* g, void* l) {
    __builtin_amdgcn_global_load_lds((gl_void*)g, (lds_void*)l, 16, 0, 0);
}

// comb[B][1024] bf16 = [input | hidden]
__global__ void convert_comb(const float* __restrict__ inp, const float* __restrict__ hid,
                             bf16_t* __restrict__ comb)
{
    size_t t = (size_t)blockIdx.x * blockDim.x + threadIdx.x;
    size_t r = t >> 7;
    int c8 = (int)(t & 127);
    const float* src = (c8 < 64) ? (inp + r * 512 + c8 * 8) : (hid + r * 512 + (c8 - 64) * 8);
    float4 a = ((const float4*)src)[0];
    float4 b = ((const float4*)src)[1];
    bf16x8 o;
    o[0] = (bf16_t)a.x; o[1] = (bf16_t)a.y; o[2] = (bf16_t)a.z; o[3] = (bf16_t)a.w;
    o[4] = (bf16_t)b.x; o[5] = (bf16_t)b.y; o[6] = (bf16_t)b.z; o[7] = (bf16_t)b.w;
    *(bf16x8*)(comb + t * 8) = o;
}

// All three weight transposes in one launch.
__global__ void transpose_all(const float* __restrict__ Wg, bf16_t* __restrict__ WgT,
                              const float* __restrict__ Wa, bf16_t* __restrict__ WaT,
                              const float* __restrict__ Mem, bf16_t* __restrict__ MemT)
{
    __shared__ float tile[32][33];
    int b = blockIdx.x;
    const float* src; bf16_t* dst; int R, C, gx;
    if (b < 2048)      { src = Wg;  dst = WgT;  R = 1024; C = 2048; gx = 64; }
    else if (b < 4096) { b -= 2048; src = Wa;  dst = WaT;  R = 512;  C = 4096; gx = 128; }
    else               { b -= 4096; src = Mem; dst = MemT; R = 4096; C = 512;  gx = 16; }
    const int x0 = (b % gx) * 32, y0 = (b / gx) * 32;
    const int tx = threadIdx.x & 31, ty = threadIdx.x >> 5;
#pragma unroll
    for (int i = 0; i < 32; i += 8)
        tile[ty + i][tx] = src[(size_t)(y0 + ty + i) * C + x0 + tx];
    __syncthreads();
#pragma unroll
    for (int i = 0; i < 32; i += 8)
        dst[(size_t)(x0 + ty + i) * R + y0 + tx] = (bf16_t)tile[tx][ty + i];
}

// C[M,N] = epi(A @ Bt^T + bias). 256x256 tile, BK=64, 8 waves (2Mx4N), 512 threads.
// Double-buffered LDS (128 KB), counted vmcnt(8) (never drains in-loop), raw barriers.
// Wave tile 128x64: acc[8][4], 64 MFMA per K-tile per wave (~600cyc compute/barrier).
// LDS rows 128B = 8 x 16B slots, swizzle slot ^= (row&7); linear glds dest +
// inverse-swizzled source + swizzled ds_read (involution). Conflicts measured 0.
template<int EPI>
__global__ __launch_bounds__(512, 2)
void gemm_w8(const bf16_t* __restrict__ A, int lda,
             const bf16_t* __restrict__ Bt, int ldb,
             const float* __restrict__ bias, int K, int N,
             bf16_t* __restrict__ bout, int ost)
{
    __shared__ __align__(16) bf16_t sA[2][256 * 64];   // 2 x 32 KB
    __shared__ __align__(16) bf16_t sB[2][256 * 64];   // 2 x 32 KB

    const int tid = threadIdx.x, lane = tid & 63, wid = tid >> 6;
    const int wr = wid >> 2, wc = wid & 3;              // 2(M) x 4(N)

    const int nwg = gridDim.x;
    int bid = (blockIdx.x & 7) * (nwg >> 3) + (blockIdx.x >> 3);  // XCD swizzle
    const int cbn = N >> 8;
    const int row0 = (bid / cbn) * 256, col0 = (bid % cbn) * 256;

    f32x4 acc[8][4] = {};
    const int nk = K >> 6;
    const int l15 = lane & 15, kq = lane >> 4;
    const int sslot = (lane & 7) ^ (lane >> 3);         // staging source swizzle

    auto stage = [&](int b, int kt) {
        const int k0 = kt << 6;
#pragma unroll
        for (int t = 0; t < 4; ++t) {                   // A,B: 32 chunks each, 4/wave
            const int c8 = wid * 4 + t;
            const int r = c8 * 8 + (lane >> 3);
            glds16(A + (size_t)(row0 + r) * lda + k0 + sslot * 8, &sA[b][c8 * 512]);
            glds16(Bt + (size_t)(col0 + r) * ldb + k0 + sslot * 8, &sB[b][c8 * 512]);
        }
    };

    auto compute = [&](int b) {
#pragma unroll
        for (int ks = 0; ks < 2; ++ks) {
            const int slot = (ks * 4 + kq) ^ (l15 & 7);
            bf16x8 bfr[4];
#pragma unroll
            for (int j = 0; j < 4; ++j) {
                const int rb = wc * 64 + j * 16 + l15;
                bfr[j] = *(const bf16x8*)&sB[b][rb * 64 + slot * 8];
            }
#pragma unroll
            for (int ih = 0; ih < 2; ++ih) {            // per-quadrant af loads cap VGPR
                bf16x8 af[4];
#pragma unroll
                for (int i = 0; i < 4; ++i) {
                    const int ra = wr * 128 + (ih * 4 + i) * 16 + l15;
                    af[i] = *(const bf16x8*)&sA[b][ra * 64 + slot * 8];
                }
#pragma unroll
                for (int i = 0; i < 4; ++i)
#pragma unroll
                    for (int j = 0; j < 4; ++j)
                        acc[ih * 4 + i][j] = __builtin_amdgcn_mfma_f32_16x16x32_bf16(
                            af[i], bfr[j], acc[ih * 4 + i][j], 0, 0, 0);
            }
        }
    };

    stage(0, 0);
    for (int kt = 0; kt < nk; ++kt) {
        if (kt + 1 < nk) {
            stage((kt + 1) & 1, kt + 1);                // 8 glds for next tile
            asm volatile("s_waitcnt vmcnt(8)" ::: "memory");  // wait cur tile only
        } else {
            asm volatile("s_waitcnt vmcnt(0)" ::: "memory");
        }
        __builtin_amdgcn_sched_barrier(0);
        __builtin_amdgcn_s_barrier();                   // buf[kt&1] ready for all
        compute(kt & 1);
        __builtin_amdgcn_sched_barrier(0);
        __builtin_amdgcn_s_barrier();                   // reads done before overwrite
    }

    const int lr = (lane >> 4) * 4, lc = lane & 15;
#pragma unroll
    for (int i = 0; i < 8; ++i) {
#pragma unroll
        for (int j = 0; j < 4; ++j) {
#pragma unroll
            for (int r = 0; r < 4; ++r) {
                const int grow = row0 + wr * 128 + i * 16 + lr + r;
                const int gcol = col0 + wc * 64 + j * 16 + lc;
                float v = acc[i][j][r] + bias[gcol];
                if constexpr (EPI == 0) {
                    const float a = ((gcol >> 9) == 2) ? tanhf(v) : sigm(v);
                    bout[(size_t)grow * 2048 + gcol] = (bf16_t)a;
                } else {
                    bout[(size_t)grow * ost + gcol] = (bf16_t)v;
                }
            }
        }
    }
}

// mr = attn_bf16 @ MemT^T fused with LSTM update. 64x256 tile, BK=64, 8 waves (2x4).
// Round-6 single-buffer structure (3-4 blocks/CU TLP covers latency here).
__global__ __launch_bounds__(512)
void gemm3k(const bf16_t* __restrict__ Ap, int astride,
            const bf16_t* __restrict__ MemT,
            const bf16_t* __restrict__ gates, const float* __restrict__ cell,
            float* __restrict__ fout)
{
    __shared__ __align__(16) bf16_t sA[64 * 64];    // 8 KB
    __shared__ __align__(16) bf16_t sB[256 * 64];   // 32 KB

    const int tid = threadIdx.x, lane = tid & 63, wid = tid >> 6;
    const int wr = wid >> 2, wc = wid & 3;

    int bid = (blockIdx.x & 7) * 64 + (blockIdx.x >> 3);   // 512 blocks
    const int row0 = (bid >> 1) * 64, col0 = (bid & 1) * 256;

    f32x4 acc[2][4] = {};
    const int l15 = lane & 15, kq = lane >> 4;

    for (int kt = 0; kt < 64; ++kt) {
        const int k0 = kt << 6;
        const int slot = (lane & 7) ^ (lane >> 3);
        {   // A: 8 chunks, 1/wave
            const int c8 = wid;
            const int r = c8 * 8 + (lane >> 3);
            glds16(Ap + (size_t)(row0 + r) * astride + k0 + slot * 8, sA + c8 * 512);
        }
#pragma unroll
        for (int t = 0; t < 4; ++t) {               // B: 32 chunks, 4/wave
            const int c8 = wid * 4 + t;
            const int r = c8 * 8 + (lane >> 3);
            glds16(MemT + (size_t)(col0 + r) * 4096 + k0 + slot * 8, sB + c8 * 512);
        }
        __syncthreads();
#pragma unroll
        for (int ks = 0; ks < 2; ++ks) {
            bf16x8 af[2], bfr[4];
            const int sl = (ks * 4 + kq) ^ (l15 & 7);
#pragma unroll
            for (int j = 0; j < 4; ++j) {
                const int rb = wc * 64 + j * 16 + l15;
                bfr[j] = *(const bf16x8*)&sB[rb * 64 + sl * 8];
            }
#pragma unroll
            for (int i = 0; i < 2; ++i) {
                const int ra = wr * 32 + i * 16 + l15;
                af[i] = *(const bf16x8*)&sA[ra * 64 + sl * 8];
            }
#pragma unroll
            for (int i = 0; i < 2; ++i)
#pragma unroll
                for (int j = 0; j < 4; ++j)
                    acc[i][j] = __builtin_amdgcn_mfma_f32_16x16x32_bf16(af[i], bfr[j], acc[i][j], 0, 0, 0);
        }
        __syncthreads();
    }

    const int lr = (lane >> 4) * 4, lc = lane & 15;
#pragma unroll
    for (int i = 0; i < 2; ++i) {
#pragma unroll
        for (int j = 0; j < 4; ++j) {
#pragma unroll
            for (int r = 0; r < 4; ++r) {
                const int grow = row0 + wr * 32 + i * 16 + lr + r;
                const int gcol = col0 + wc * 64 + j * 16 + lc;
                const float v = acc[i][j][r];
                const float ig = (float)gates[(size_t)grow * 2048 + gcol];
                const float fg = (float)gates[(size_t)grow * 2048 + 512 + gcol];
                const float cg = (float)gates[(size_t)grow * 2048 + 1024 + gcol];
                const float og = (float)gates[(size_t)grow * 2048 + 1536 + gcol];
                const float cv = cell[(size_t)grow * 512 + gcol];
                const float ncv = fg * cv + ig * cg + 0.1f * v;
                fout[(size_t)grow * 512 + gcol] = og * tanhf(ncv);
                fout[(size_t)Bn * Hn + (size_t)grow * 512 + gcol] = ncv;
            }
        }
    }
}

// Row softmax over packed bf16 logits (stride pstride). Writes bf16 attn back in
// place; if F32OUT also writes the full fp32 attn row to attnf32.
template<bool F32OUT>
__global__ void softmax_k(bf16_t* __restrict__ packed, int pstride, float* __restrict__ attnf32)
{
    const int row = blockIdx.x;
    bf16_t* lp = packed + (size_t)row * pstride;
    const int tid = threadIdx.x;

    float v[16];
    {
        bf16x8 h0 = ((const bf16x8*)lp)[tid];
        bf16x8 h1 = ((const bf16x8*)lp)[tid + 256];
#pragma unroll
        for (int k = 0; k < 8; ++k) { v[k] = (float)h0[k]; v[8 + k] = (float)h1[k]; }
    }
    float mx = v[0];
#pragma unroll
    for (int k = 1; k < 16; ++k) mx = fmaxf(mx, v[k]);
#pragma unroll
    for (int off = 32; off > 0; off >>= 1) mx = fmaxf(mx, __shfl_xor(mx, off));
    __shared__ float smx[4], ssm[4];
    if ((tid & 63) == 0) smx[tid >> 6] = mx;
    __syncthreads();
    mx = fmaxf(fmaxf(smx[0], smx[1]), fmaxf(smx[2], smx[3]));

    float sum = 0.0f;
#pragma unroll
    for (int k = 0; k < 16; ++k) { v[k] = __expf(v[k] - mx); sum += v[k]; }
#pragma unroll
    for (int off = 32; off > 0; off >>= 1) sum += __shfl_xor(sum, off);
    if ((tid & 63) == 0) ssm[tid >> 6] = sum;
    __syncthreads();
    sum = ssm[0] + ssm[1] + ssm[2] + ssm[3];

    const float inv = 1.0f / sum;
#pragma unroll
    for (int k = 0; k < 16; ++k) v[k] *= inv;

    bf16x8 o0, o1;
#pragma unroll
    for (int k = 0; k < 8; ++k) { o0[k] = (bf16_t)v[k]; o1[k] = (bf16_t)v[8 + k]; }
    ((bf16x8*)lp)[tid]       = o0;
    ((bf16x8*)lp)[tid + 256] = o1;

    if constexpr (F32OUT) {
        float* rp = attnf32 + (size_t)row * 4096;
        float4 a0 = { v[0], v[1], v[2], v[3] },   a1 = { v[4], v[5], v[6], v[7] };
        float4 a2 = { v[8], v[9], v[10], v[11] }, a3 = { v[12], v[13], v[14], v[15] };
        ((float4*)rp)[2 * tid]             = a0;
        ((float4*)rp)[2 * tid + 1]         = a1;
        ((float4*)rp)[2 * (tid + 256)]     = a2;
        ((float4*)rp)[2 * (tid + 256) + 1] = a3;
    }
}

// Expand packed bf16 attn row (first half) -> full fp32 row, in place (fallback).
__global__ void expand_attn(float* __restrict__ attn)
{
    const int row = blockIdx.x;
    float* rp = attn + (size_t)row * 4096;
    const int t = threadIdx.x;
    bf16x8 h0 = ((const bf16x8*)rp)[2 * t];
    bf16x8 h1 = ((const bf16x8*)rp)[2 * t + 1];
    __syncthreads();
    float4 o0 = { (float)h0[0], (float)h0[1], (float)h0[2], (float)h0[3] };
    float4 o1 = { (float)h0[4], (float)h0[5], (float)h0[6], (float)h0[7] };
    float4 o2 = { (float)h1[0], (float)h1[1], (float)h1[2], (float)h1[3] };
    float4 o3 = { (float)h1[4], (float)h1[5], (float)h1[6], (float)h1[7] };
    ((float4*)rp)[4 * t]     = o0;
    ((float4*)rp)[4 * t + 1] = o1;
    ((float4*)rp)[4 * t + 2] = o2;
    ((float4*)rp)[4 * t + 3] = o3;
}

extern "C" void kernel_launch(void* const* d_in, const int* in_sizes, int n_in,
                              void* d_out, int out_size, void* d_ws, size_t ws_size,
                              hipStream_t stream)
{
    const float* input  = (const float*)d_in[0];
    const float* hidden = (const float*)d_in[1];
    const float* cell   = (const float*)d_in[2];
    const float* Wg     = (const float*)d_in[3];
    const float* bg     = (const float*)d_in[4];
    const float* Wa     = (const float*)d_in[5];
    const float* ba     = (const float*)d_in[6];
    const float* Mem    = (const float*)d_in[7];

    float* out  = (float*)d_out;
    float* attn = out + 2ull * Bn * Hn;

    bf16_t* comb  = (bf16_t*)d_ws;                 // [B][1024]      33.5 MB
    bf16_t* WgT   = comb + (size_t)Bn * 1024;      // [2048][1024]    4.2
    bf16_t* WaT   = WgT + (size_t)2048 * 1024;     // [4096][512]     4.2
    bf16_t* MemT  = WaT + (size_t)4096 * 512;      // [512][4096]     4.2
    bf16_t* gates = MemT + (size_t)512 * 4096;     // [B][2048]      67.1
    bf16_t* pws   = gates + (size_t)Bn * 2048;     // [B][4096]     134.2 (big path)

    const size_t need_big = ((size_t)Bn * 1024 + 2048 * 1024 + 4096 * 512 + 512 * 4096
                             + (size_t)Bn * 2048 + (size_t)Bn * 4096) * sizeof(bf16_t);
    const bool big = ws_size >= need_big;
    bf16_t* packed = big ? pws : (bf16_t*)attn;
    const int pstride = big ? 4096 : 8192;

    convert_comb<<<8192, 256, 0, stream>>>(input, hidden, comb);
    transpose_all<<<6144, 256, 0, stream>>>(Wg, WgT, Wa, WaT, Mem, MemT);

    // gates = act([x|h] @ Wg + bg): 256x256 tiles, grid 64x8
    gemm_w8<0><<<512, 512, 0, stream>>>(comb, 1024, WgT, 1024, bg, 1024, 2048, gates, 2048);
    // logits = h @ Wa + ba (packed bf16): 256x256 tiles, grid 64x16
    gemm_w8<1><<<1024, 512, 0, stream>>>(comb + 512, 1024, WaT, 512, ba, 512, 4096,
                                         packed, pstride);

    if (big) softmax_k<true><<<Bn, 256, 0, stream>>>(packed, pstride, attn);
    else     softmax_k<false><<<Bn, 256, 0, stream>>>(packed, pstride, nullptr);

    // mr = attn @ Mem fused with LSTM update: 64x256 tiles, grid 256x2
    gemm3k<<<512, 512, 0, stream>>>(packed, pstride, MemT, gates, cell, out);

    if (!big) expand_attn<<<Bn, 256, 0, stream>>>(attn);
}

// Round 9
// 490.930 us; speedup vs baseline: 1.0489x; 1.0034x over previous
//
#include <hip/hip_runtime.h>
#include <hip/hip_bf16.h>
#include <math.h>

typedef __bf16 bf16_t;
typedef bf16_t bf16x8 __attribute__((ext_vector_type(8)));
typedef float  f32x4  __attribute__((ext_vector_type(4)));

static constexpr int Bn = 16384;
static constexpr int Hn = 512;

__device__ __forceinline__ float sigm(float x) { return 1.0f / (1.0f + __expf(-x)); }

typedef __attribute__((address_space(3))) void lds_void;
typedef const __attribute__((address_space(1))) void gl_void;

__device__ __forceinline__ void glds16(const void* g, void* l) {
    __builtin_amdgcn_global_load_lds((gl_void*)g, (lds_void*)l, 16, 0, 0);
}

// comb[B][1024] bf16 = [input | hidden]
__global__ void convert_comb(const float* __restrict__ inp, const float* __restrict__ hid,
                             bf16_t* __restrict__ comb)
{
    size_t t = (size_t)blockIdx.x * blockDim.x + threadIdx.x;
    size_t r = t >> 7;
    int c8 = (int)(t & 127);
    const float* src = (c8 < 64) ? (inp + r * 512 + c8 * 8) : (hid + r * 512 + (c8 - 64) * 8);
    float4 a = ((const float4*)src)[0];
    float4 b = ((const float4*)src)[1];
    bf16x8 o;
    o[0] = (bf16_t)a.x; o[1] = (bf16_t)a.y; o[2] = (bf16_t)a.z; o[3] = (bf16_t)a.w;
    o[4] = (bf16_t)b.x; o[5] = (bf16_t)b.y; o[6] = (bf16_t)b.z; o[7] = (bf16_t)b.w;
    *(bf16x8*)(comb + t * 8) = o;
}

// All three weight transposes in one launch.
__global__ void transpose_all(const float* __restrict__ Wg, bf16_t* __restrict__ WgT,
                              const float* __restrict__ Wa, bf16_t* __restrict__ WaT,
                              const float* __restrict__ Mem, bf16_t* __restrict__ MemT)
{
    __shared__ float tile[32][33];
    int b = blockIdx.x;
    const float* src; bf16_t* dst; int R, C, gx;
    if (b < 2048)      { src = Wg;  dst = WgT;  R = 1024; C = 2048; gx = 64; }
    else if (b < 4096) { b -= 2048; src = Wa;  dst = WaT;  R = 512;  C = 4096; gx = 128; }
    else               { b -= 4096; src = Mem; dst = MemT; R = 4096; C = 512;  gx = 16; }
    const int x0 = (b % gx) * 32, y0 = (b / gx) * 32;
    const int tx = threadIdx.x & 31, ty = threadIdx.x >> 5;
#pragma unroll
    for (int i = 0; i < 32; i += 8)
        tile[ty + i][tx] = src[(size_t)(y0 + ty + i) * C + x0 + tx];
    __syncthreads();
#pragma unroll
    for (int i = 0; i < 32; i += 8)
        dst[(size_t)(x0 + ty + i) * R + y0 + tx] = (bf16_t)tile[tx][ty + i];
}

// ---------------- 8-phase 256x256 GEMM (T3+T4+T5) ----------------
// BM=BN=256, BK=64, 8 waves (2M x 4N), wave tile 128x64, acc[8][4].
// LDS 128KB dynamic: [mat A|B][dbuf 0|1][khalf 0|1][128 prow][64 bf16].
//   K-half layout: elem (row R=mh*128+prow, k=kh*32+q*8+e) lives at
//   prow*64 + ((mh*4+q)^(prow&7))*8  -- XOR involution, 2-way conflicts only.
// Per K-tile, 4 MFMA phases in order (ks0,hi0),(ks0,hi1),(ks1,hi0),(ks1,hi1)
//   -> kh0 slots free after phase 2, kh1 after phase 4.
// Stage schedule (iter consumes tiles e=2i (dbuf0, ph1-4), o=2i+1 (dbuf1, ph5-8);
// stages en=2i+2 -> dbuf0, on=2i+3 -> dbuf1):
//   ph1:A(d1,kh1,o) ph2:B(d1,kh1,o) ph3:A(d0,kh0,en) ph4:B(d0,kh0,en)+vmcnt(4)
//   ph5:A(d0,kh1,en) ph6:B(d0,kh1,en) ph7:A(d1,kh0,on) ph8:B(d1,kh0,on)+vmcnt(4)
// Guarantees (each verified): vmcnt(4)@ph4 leaves {ph3,ph4} -> o.kh1 (ph1,2) and
// o.kh0 (prev ph7,8) landed before ph5/ph7 use; vmcnt(4)@ph8 leaves {ph7,ph8} ->
// en.kh0 (ph3,4) and en.kh1 (ph5,6) landed before next ph1/ph3 use.
// Prologue: stage T0 (4 halves) + T1.kh0 (2 halves); vmcnt(4) -> T0 landed.
// Last iter: stage only o.kh1 at ph1,2; vmcnt(0) at ph4; no ph8 wait.
#define VM4 do { asm volatile("s_waitcnt vmcnt(4)" ::: "memory"); \
                 __builtin_amdgcn_sched_barrier(0); } while (0)
#define VM0 do { asm volatile("s_waitcnt vmcnt(0)" ::: "memory"); \
                 __builtin_amdgcn_sched_barrier(0); } while (0)
#define NOP ((void)0)

#define PH(d, ks, hi, READB, STAGE, WAIT) do {                                     \
    bf16x8 af_[4];                                                                 \
    _Pragma("unroll")                                                              \
    for (int ii = 0; ii < 4; ++ii)                                                 \
        af_[ii] = *(const bf16x8*)&lds[(d)*16384 + (ks)*8192 +                     \
                                       ((hi)*64 + ii*16)*64 + abr];                \
    if (READB) {                                                                   \
        _Pragma("unroll")                                                          \
        for (int j = 0; j < 4; ++j)                                                \
            bfr[j] = *(const bf16x8*)&lds[32768 + (d)*16384 + (ks)*8192 +          \
                                          j*1024 + bbr];                           \
    }                                                                              \
    STAGE;                                                                         \
    WAIT;                                                                          \
    __builtin_amdgcn_s_barrier();                                                  \
    __builtin_amdgcn_s_setprio(1);                                                 \
    _Pragma("unroll")                                                              \
    for (int ii = 0; ii < 4; ++ii)                                                 \
        _Pragma("unroll")                                                          \
        for (int j = 0; j < 4; ++j)                                                \
            acc[(hi)*4 + ii][j] = __builtin_amdgcn_mfma_f32_16x16x32_bf16(         \
                af_[ii], bfr[j], acc[(hi)*4 + ii][j], 0, 0, 0);                    \
    __builtin_amdgcn_s_setprio(0);                                                 \
    __builtin_amdgcn_s_barrier();                                                  \
    __builtin_amdgcn_sched_barrier(0);                                             \
} while (0)

template<int EPI>
__global__ __launch_bounds__(512, 2)
void gemm8p(const bf16_t* __restrict__ A, int lda,
            const bf16_t* __restrict__ Bt, int ldb,
            const float* __restrict__ bias, int K, int N,
            bf16_t* __restrict__ bout, int ost)
{
    extern __shared__ __align__(16) bf16_t lds[];   // 128 KB

    const int tid = threadIdx.x, lane = tid & 63, wid = tid >> 6;
    const int wr = wid >> 2, wc = wid & 3;
    const int l15 = lane & 15, kq = lane >> 4;

    const int nwg = gridDim.x;
    int bid = (blockIdx.x & 7) * (nwg >> 3) + (blockIdx.x >> 3);  // XCD swizzle
    const int cbn = N >> 8;
    const int row0 = (bid / cbn) * 256, col0 = (bid % cbn) * 256;

    // staging per-thread constants: chunk c8 = wid*2+t covers prows c8*8..+8
    const int sl  = (lane & 7) ^ (lane >> 3);       // logical slot = mh*4 + q
    const int smh = sl >> 2, sq = sl & 3;
    size_t goffA[2], goffB[2];
    int ldsoff[2];
#pragma unroll
    for (int t = 0; t < 2; ++t) {
        const int c8 = wid * 2 + t;
        const int prow = c8 * 8 + (lane >> 3);
        goffA[t] = (size_t)(row0 + smh * 128 + prow) * lda + sq * 8;
        goffB[t] = (size_t)(col0 + smh * 128 + prow) * ldb + sq * 8;
        ldsoff[t] = c8 * 512;
    }

    // fragment-read per-thread constants
    const int abr = l15 * 64 + (((wr * 4 + kq) ^ (l15 & 7)) * 8);
    const int bbr = ((wc & 1) * 64 + l15) * 64 + ((((wc >> 1) * 4 + kq) ^ (l15 & 7)) * 8);

    auto stageA = [&](int d, int kh, int kt) {
        const int koff = kt * 64 + kh * 32;
#pragma unroll
        for (int t = 0; t < 2; ++t)
            glds16(A + goffA[t] + koff, lds + d * 16384 + kh * 8192 + ldsoff[t]);
    };
    auto stageB = [&](int d, int kh, int kt) {
        const int koff = kt * 64 + kh * 32;
#pragma unroll
        for (int t = 0; t < 2; ++t)
            glds16(Bt + goffB[t] + koff, lds + 32768 + d * 16384 + kh * 8192 + ldsoff[t]);
    };

    f32x4 acc[8][4] = {};
    bf16x8 bfr[4];

    // prologue: T0 full + T1.kh0
    stageA(0, 0, 0); stageB(0, 0, 0); stageA(0, 1, 0); stageB(0, 1, 0);
    stageA(1, 0, 1); stageB(1, 0, 1);
    VM4;                                            // T0 (8 oldest) landed
    __builtin_amdgcn_s_barrier();

    const int niter = K >> 7;                       // 2 K-tiles per iter
    for (int it = 0; it < niter - 1; ++it) {
        const int o = 2 * it + 1, e2 = 2 * it + 2, o2 = 2 * it + 3;
        PH(0, 0, 0, 1, stageA(1, 1, o),  NOP);
        PH(0, 0, 1, 0, stageB(1, 1, o),  NOP);
        PH(0, 1, 0, 1, stageA(0, 0, e2), NOP);
        PH(0, 1, 1, 0, stageB(0, 0, e2), VM4);
        PH(1, 0, 0, 1, stageA(0, 1, e2), NOP);
        PH(1, 0, 1, 0, stageB(0, 1, e2), NOP);
        PH(1, 1, 0, 1, stageA(1, 0, o2), NOP);
        PH(1, 1, 1, 0, stageB(1, 0, o2), VM4);
    }
    {   // last iter: no en/on tiles
        const int o = 2 * niter - 1;
        PH(0, 0, 0, 1, stageA(1, 1, o), NOP);
        PH(0, 0, 1, 0, stageB(1, 1, o), NOP);
        PH(0, 1, 0, 1, NOP, NOP);
        PH(0, 1, 1, 0, NOP, VM0);
        PH(1, 0, 0, 1, NOP, NOP);
        PH(1, 0, 1, 0, NOP, NOP);
        PH(1, 1, 0, 1, NOP, NOP);
        PH(1, 1, 1, 0, NOP, NOP);
    }

    // epilogue: C/D layout col = lane&15, row = 4*(lane>>4)+reg
    const int lr = (lane >> 4) * 4, lc = lane & 15;
#pragma unroll
    for (int i = 0; i < 8; ++i) {
#pragma unroll
        for (int j = 0; j < 4; ++j) {
#pragma unroll
            for (int r = 0; r < 4; ++r) {
                const int grow = row0 + wr * 128 + i * 16 + lr + r;
                const int gcol = col0 + wc * 64 + j * 16 + lc;
                float v = acc[i][j][r] + bias[gcol];
                if constexpr (EPI == 0) {
                    const float a = ((gcol >> 9) == 2) ? tanhf(v) : sigm(v);
                    bout[(size_t)grow * 2048 + gcol] = (bf16_t)a;
                } else {
                    bout[(size_t)grow * ost + gcol] = (bf16_t)v;
                }
            }
        }
    }
}

// mr = attn_bf16 @ MemT^T fused with LSTM update. 64x256 tile, BK=64, 8 waves (2x4).
// Round-6 single-buffer structure (3+ blocks/CU TLP covers latency here).
__global__ __launch_bounds__(512)
void gemm3k(const bf16_t* __restrict__ Ap, int astride,
            const bf16_t* __restrict__ MemT,
            const bf16_t* __restrict__ gates, const float* __restrict__ cell,
            float* __restrict__ fout)
{
    __shared__ __align__(16) bf16_t sA[64 * 64];    // 8 KB
    __shared__ __align__(16) bf16_t sB[256 * 64];   // 32 KB

    const int tid = threadIdx.x, lane = tid & 63, wid = tid >> 6;
    const int wr = wid >> 2, wc = wid & 3;

    int bid = (blockIdx.x & 7) * 64 + (blockIdx.x >> 3);   // 512 blocks
    const int row0 = (bid >> 1) * 64, col0 = (bid & 1) * 256;

    f32x4 acc[2][4] = {};
    const int l15 = lane & 15, kq = lane >> 4;

    for (int kt = 0; kt < 64; ++kt) {
        const int k0 = kt << 6;
        const int slot = (lane & 7) ^ (lane >> 3);
        {   // A: 8 chunks, 1/wave
            const int c8 = wid;
            const int r = c8 * 8 + (lane >> 3);
            glds16(Ap + (size_t)(row0 + r) * astride + k0 + slot * 8, sA + c8 * 512);
        }
#pragma unroll
        for (int t = 0; t < 4; ++t) {               // B: 32 chunks, 4/wave
            const int c8 = wid * 4 + t;
            const int r = c8 * 8 + (lane >> 3);
            glds16(MemT + (size_t)(col0 + r) * 4096 + k0 + slot * 8, sB + c8 * 512);
        }
        __syncthreads();
#pragma unroll
        for (int ks = 0; ks < 2; ++ks) {
            bf16x8 af[2], bfr[4];
            const int sl = (ks * 4 + kq) ^ (l15 & 7);
#pragma unroll
            for (int j = 0; j < 4; ++j) {
                const int rb = wc * 64 + j * 16 + l15;
                bfr[j] = *(const bf16x8*)&sB[rb * 64 + sl * 8];
            }
#pragma unroll
            for (int i = 0; i < 2; ++i) {
                const int ra = wr * 32 + i * 16 + l15;
                af[i] = *(const bf16x8*)&sA[ra * 64 + sl * 8];
            }
#pragma unroll
            for (int i = 0; i < 2; ++i)
#pragma unroll
                for (int j = 0; j < 4; ++j)
                    acc[i][j] = __builtin_amdgcn_mfma_f32_16x16x32_bf16(af[i], bfr[j], acc[i][j], 0, 0, 0);
        }
        __syncthreads();
    }

    const int lr = (lane >> 4) * 4, lc = lane & 15;
#pragma unroll
    for (int i = 0; i < 2; ++i) {
#pragma unroll
        for (int j = 0; j < 4; ++j) {
#pragma unroll
            for (int r = 0; r < 4; ++r) {
                const int grow = row0 + wr * 32 + i * 16 + lr + r;
                const int gcol = col0 + wc * 64 + j * 16 + lc;
                const float v = acc[i][j][r];
                const float ig = (float)gates[(size_t)grow * 2048 + gcol];
                const float fg = (float)gates[(size_t)grow * 2048 + 512 + gcol];
                const float cg = (float)gates[(size_t)grow * 2048 + 1024 + gcol];
                const float og = (float)gates[(size_t)grow * 2048 + 1536 + gcol];
                const float cv = cell[(size_t)grow * 512 + gcol];
                const float ncv = fg * cv + ig * cg + 0.1f * v;
                fout[(size_t)grow * 512 + gcol] = og * tanhf(ncv);
                fout[(size_t)Bn * Hn + (size_t)grow * 512 + gcol] = ncv;
            }
        }
    }
}

// Row softmax over packed bf16 logits (stride pstride). Writes bf16 attn back in
// place; if F32OUT also writes the full fp32 attn row to attnf32.
template<bool F32OUT>
__global__ void softmax_k(bf16_t* __restrict__ packed, int pstride, float* __restrict__ attnf32)
{
    const int row = blockIdx.x;
    bf16_t* lp = packed + (size_t)row * pstride;
    const int tid = threadIdx.x;

    float v[16];
    {
        bf16x8 h0 = ((const bf16x8*)lp)[tid];
        bf16x8 h1 = ((const bf16x8*)lp)[tid + 256];
#pragma unroll
        for (int k = 0; k < 8; ++k) { v[k] = (float)h0[k]; v[8 + k] = (float)h1[k]; }
    }
    float mx = v[0];
#pragma unroll
    for (int k = 1; k < 16; ++k) mx = fmaxf(mx, v[k]);
#pragma unroll
    for (int off = 32; off > 0; off >>= 1) mx = fmaxf(mx, __shfl_xor(mx, off));
    __shared__ float smx[4], ssm[4];
    if ((tid & 63) == 0) smx[tid >> 6] = mx;
    __syncthreads();
    mx = fmaxf(fmaxf(smx[0], smx[1]), fmaxf(smx[2], smx[3]));

    float sum = 0.0f;
#pragma unroll
    for (int k = 0; k < 16; ++k) { v[k] = __expf(v[k] - mx); sum += v[k]; }
#pragma unroll
    for (int off = 32; off > 0; off >>= 1) sum += __shfl_xor(sum, off);
    if ((tid & 63) == 0) ssm[tid >> 6] = sum;
    __syncthreads();
    sum = ssm[0] + ssm[1] + ssm[2] + ssm[3];

    const float inv = 1.0f / sum;
#pragma unroll
    for (int k = 0; k < 16; ++k) v[k] *= inv;

    bf16x8 o0, o1;
#pragma unroll
    for (int k = 0; k < 8; ++k) { o0[k] = (bf16_t)v[k]; o1[k] = (bf16_t)v[8 + k]; }
    ((bf16x8*)lp)[tid]       = o0;
    ((bf16x8*)lp)[tid + 256] = o1;

    if constexpr (F32OUT) {
        float* rp = attnf32 + (size_t)row * 4096;
        float4 a0 = { v[0], v[1], v[2], v[3] },   a1 = { v[4], v[5], v[6], v[7] };
        float4 a2 = { v[8], v[9], v[10], v[11] }, a3 = { v[12], v[13], v[14], v[15] };
        ((float4*)rp)[2 * tid]             = a0;
        ((float4*)rp)[2 * tid + 1]         = a1;
        ((float4*)rp)[2 * (tid + 256)]     = a2;
        ((float4*)rp)[2 * (tid + 256) + 1] = a3;
    }
}

// Expand packed bf16 attn row (first half) -> full fp32 row, in place (fallback).
__global__ void expand_attn(float* __restrict__ attn)
{
    const int row = blockIdx.x;
    float* rp = attn + (size_t)row * 4096;
    const int t = threadIdx.x;
    bf16x8 h0 = ((const bf16x8*)rp)[2 * t];
    bf16x8 h1 = ((const bf16x8*)rp)[2 * t + 1];
    __syncthreads();
    float4 o0 = { (float)h0[0], (float)h0[1], (float)h0[2], (float)h0[3] };
    float4 o1 = { (float)h0[4], (float)h0[5], (float)h0[6], (float)h0[7] };
    float4 o2 = { (float)h1[0], (float)h1[1], (float)h1[2], (float)h1[3] };
    float4 o3 = { (float)h1[4], (float)h1[5], (float)h1[6], (float)h1[7] };
    ((float4*)rp)[4 * t]     = o0;
    ((float4*)rp)[4 * t + 1] = o1;
    ((float4*)rp)[4 * t + 2] = o2;
    ((float4*)rp)[4 * t + 3] = o3;
}

extern "C" void kernel_launch(void* const* d_in, const int* in_sizes, int n_in,
                              void* d_out, int out_size, void* d_ws, size_t ws_size,
                              hipStream_t stream)
{
    const float* input  = (const float*)d_in[0];
    const float* hidden = (const float*)d_in[1];
    const float* cell   = (const float*)d_in[2];
    const float* Wg     = (const float*)d_in[3];
    const float* bg     = (const float*)d_in[4];
    const float* Wa     = (const float*)d_in[5];
    const float* ba     = (const float*)d_in[6];
    const float* Mem    = (const float*)d_in[7];

    float* out  = (float*)d_out;
    float* attn = out + 2ull * Bn * Hn;

    bf16_t* comb  = (bf16_t*)d_ws;                 // [B][1024]      33.5 MB
    bf16_t* WgT   = comb + (size_t)Bn * 1024;      // [2048][1024]    4.2
    bf16_t* WaT   = WgT + (size_t)2048 * 1024;     // [4096][512]     4.2
    bf16_t* MemT  = WaT + (size_t)4096 * 512;      // [512][4096]     4.2
    bf16_t* gates = MemT + (size_t)512 * 4096;     // [B][2048]      67.1
    bf16_t* pws   = gates + (size_t)Bn * 2048;     // [B][4096]     134.2 (big path)

    const size_t need_big = ((size_t)Bn * 1024 + 2048 * 1024 + 4096 * 512 + 512 * 4096
                             + (size_t)Bn * 2048 + (size_t)Bn * 4096) * sizeof(bf16_t);
    const bool big = ws_size >= need_big;
    bf16_t* packed = big ? pws : (bf16_t*)attn;
    const int pstride = big ? 4096 : 8192;

    // allow 128KB dynamic LDS for the 8-phase kernels (host-side, graph-safe)
    hipFuncSetAttribute((const void*)gemm8p<0>,
                        hipFuncAttributeMaxDynamicSharedMemorySize, 131072);
    hipFuncSetAttribute((const void*)gemm8p<1>,
                        hipFuncAttributeMaxDynamicSharedMemorySize, 131072);

    convert_comb<<<8192, 256, 0, stream>>>(input, hidden, comb);
    transpose_all<<<6144, 256, 0, stream>>>(Wg, WgT, Wa, WaT, Mem, MemT);

    // gates = act([x|h] @ Wg + bg): 256x256 tiles, grid 64x8
    gemm8p<0><<<512, 512, 131072, stream>>>(comb, 1024, WgT, 1024, bg, 1024, 2048,
                                            gates, 2048);
    // logits = h @ Wa + ba (packed bf16): 256x256 tiles, grid 64x16
    gemm8p<1><<<1024, 512, 131072, stream>>>(comb + 512, 1024, WaT, 512, ba, 512, 4096,
                                             packed, pstride);

    if (big) softmax_k<true><<<Bn, 256, 0, stream>>>(packed, pstride, attn);
    else     softmax_k<false><<<Bn, 256, 0, stream>>>(packed, pstride, nullptr);

    // mr = attn @ Mem fused with LSTM update: 64x256 tiles, grid 256x2
    gemm3k<<<512, 512, 0, stream>>>(packed, pstride, MemT, gates, cell, out);

    if (!big) expand_attn<<<Bn, 256, 0, stream>>>(attn);
}